// Round 1
// baseline (335.512 us; speedup 1.0000x reference)
//
#include <hip/hip_runtime.h>
#include <cstdint>
#include <cfloat>

// Sample grid: round(linspace(0,63,16)) -- verified no .5 cases, fp32/fp64 agree.
__constant__ int c_smp[16] = {0,4,8,13,17,21,25,29,34,38,42,46,50,55,59,63};

// Problem constants
static constexpr int NB   = 32;    // batch
static constexpr int NC   = 64;    // C1 channels after unshuffle
static constexpr int NH   = 64;    // H1
static constexpr int NTOK = 4096;  // H1*W1
static constexpr int NM   = 256;   // samples
static constexpr int NK   = 3;     // neighbors

// ---------------------------------------------------------------------------
// Kernel 1: gather x_sample in two layouts:
//   xs_t[b][c][m]  (c-major, for distance GEMM staging)
//   xs_m[b][m][c]  (m-major, for scalar-uniform reads in k_z)
// ---------------------------------------------------------------------------
__global__ __launch_bounds__(256) void k_xs(const float* __restrict__ x,
                                            float* __restrict__ xs_t,
                                            float* __restrict__ xs_m) {
    int b = blockIdx.x;
    int m = threadIdx.x;                 // 256 samples
    int gi = m >> 4, gj = m & 15;
    int hh = c_smp[gi], ww = c_smp[gj];
    const float* xb = x + (size_t)b * 16 * 128 * 128;
    float* xtm = xs_m + ((size_t)b * NM + m) * NC;
    for (int c1 = 0; c1 < NC; ++c1) {
        int c = c1 >> 2, sh = (c1 >> 1) & 1, sw = c1 & 1;
        float v = xb[((size_t)c * 128 + (2 * hh + sh)) * 128 + (2 * ww + sw)];
        xs_t[((size_t)b * NC + c1) * NM + m] = v;   // coalesced over m
        xtm[c1] = v;
    }
}

// ---------------------------------------------------------------------------
// Kernel 2: Z[b][k][m][o] = sum_c w[o][c][k] * xs[b][m][c]
// lane = o (64), weights held in 64 VGPRs, xs row read as wave-uniform scalars.
// grid = NB*3*16 blocks of 64 threads; each block does 16 m's.
// ---------------------------------------------------------------------------
__global__ __launch_bounds__(64) void k_z(const float* __restrict__ xs_m,
                                          const float* __restrict__ w,
                                          float* __restrict__ Z) {
    int bid = blockIdx.x;            // NB*3*16
    int mg  = bid & 15;
    int k   = (bid >> 4) % 3;
    int b   = bid / 48;
    int o   = threadIdx.x;           // 64
    float wf[64];
#pragma unroll
    for (int c = 0; c < 64; ++c) wf[c] = w[((size_t)o * 64 + c) * 3 + k];
    const float* xb = xs_m + (size_t)b * NM * NC;
    float* zb = Z + ((size_t)b * 3 + k) * NM * NC;
    for (int mm = 0; mm < 16; ++mm) {
        int m = mg * 16 + mm;
        const float* xr = xb + (size_t)m * NC;   // wave-uniform address
        float acc = 0.f;
#pragma unroll
        for (int c = 0; c < 64; ++c) acc = fmaf(wf[c], xr[c], acc);
        zb[(size_t)m * NC + o] = acc;            // coalesced over o
    }
}

// ---------------------------------------------------------------------------
// Kernel 3: distances + top-3 selection.
// Block = 64 tokens (one h-row of one batch) x all 256 samples, K chunked by 32.
// Thread (r = t>>5 in 0..7, cl = t&31): 8 tokens x 8 samples register tile.
// Selection: per-thread top-3 insert + 5-step shfl_xor butterfly over 32 lanes.
// Tie semantics match lax.top_k: lexicographic (d2, m) ascending.
// ---------------------------------------------------------------------------
#define LESS_E(ad, am, bd, bm) ((ad) < (bd) || ((ad) == (bd) && (am) < (bm)))
#define INSERT_E(xd, xm)                                                        \
    do {                                                                        \
        float _xd = (xd); int _xm = (xm);                                       \
        if (LESS_E(_xd, _xm, e2d, e2m)) {                                       \
            e2d = _xd; e2m = _xm;                                               \
            if (LESS_E(e2d, e2m, e1d, e1m)) {                                   \
                float td = e1d; int tm = e1m; e1d = e2d; e1m = e2m;             \
                e2d = td; e2m = tm;                                             \
                if (LESS_E(e1d, e1m, e0d, e0m)) {                               \
                    float sd = e0d; int sm = e0m; e0d = e1d; e0m = e1m;         \
                    e1d = sd; e1m = sm;                                         \
                }                                                               \
            }                                                                   \
        }                                                                       \
    } while (0)

__global__ __launch_bounds__(256) void k_dist(const float* __restrict__ x,
                                              const float* __restrict__ xs_t,
                                              int* __restrict__ idx) {
    __shared__ __align__(16) float att[32][64];    // 8 KB  A chunk [c][n]
    __shared__ __align__(16) float xsT[32][256];   // 32 KB B chunk [c][m]
    __shared__ float m2l[256];
    __shared__ float n2l[64];

    int b = blockIdx.x >> 6;
    int h = blockIdx.x & 63;
    int t = threadIdx.x;
    int r = t >> 5, cl = t & 31;

    float acc[8][8];
#pragma unroll
    for (int i = 0; i < 8; ++i)
#pragma unroll
        for (int j = 0; j < 8; ++j) acc[i][j] = 0.f;

    float m2acc = 0.f, n2acc = 0.f;
    const float* xb = x + (size_t)b * 16 * 128 * 128;
    const float* xsb = xs_t + (size_t)b * NC * NM;

    for (int kc = 0; kc < 2; ++kc) {
        __syncthreads();
        // A chunk: att[c1-kc*32][w] from x with unshuffle fold. float2 covers sw={0,1}.
#pragma unroll
        for (int it = 0; it < 4; ++it) {
            int i = t + it * 256;          // 0..1023
            int p = i >> 6;                // 0..15 (c1 pair)
            int wcol = i & 63;
            int c1e = kc * 32 + p * 2;
            int c = c1e >> 2, sh = (c1e >> 1) & 1;
            const float* src = xb + ((size_t)c * 128 + (2 * h + sh)) * 128 + 2 * wcol;
            float2 v = *(const float2*)src;
            att[p * 2 + 0][wcol] = v.x;
            att[p * 2 + 1][wcol] = v.y;
        }
        // B chunk: xsT rows kc*32..+31 from xs_t, float4 coalesced.
#pragma unroll
        for (int it = 0; it < 8; ++it) {
            int f4 = t + it * 256;         // 0..2047
            int row = f4 >> 6;
            int c4 = (f4 & 63) * 4;
            *(float4*)&xsT[row][c4] =
                *(const float4*)&xsb[(size_t)(kc * 32 + row) * NM + c4];
        }
        __syncthreads();

        // m2 / n2 partials (sequential ascending c, mul then add like np).
        for (int c = 0; c < 32; ++c) {
            float v = xsT[c][t];
            m2acc = __fadd_rn(m2acc, __fmul_rn(v, v));
        }
        if (t < 64) {
            for (int c = 0; c < 32; ++c) {
                float v = att[c][t];
                n2acc = __fadd_rn(n2acc, __fmul_rn(v, v));
            }
        }

        // dot accumulation: 8x8 register tile
#pragma unroll 4
        for (int k = 0; k < 32; ++k) {
            float4 a0 = *(const float4*)&att[k][r * 8];
            float4 a1 = *(const float4*)&att[k][r * 8 + 4];
            float4 b0 = *(const float4*)&xsT[k][cl * 8];
            float4 b1 = *(const float4*)&xsT[k][cl * 8 + 4];
            float av[8] = {a0.x, a0.y, a0.z, a0.w, a1.x, a1.y, a1.z, a1.w};
            float bv[8] = {b0.x, b0.y, b0.z, b0.w, b1.x, b1.y, b1.z, b1.w};
#pragma unroll
            for (int i = 0; i < 8; ++i)
#pragma unroll
                for (int j = 0; j < 8; ++j)
                    acc[i][j] = fmaf(av[i], bv[j], acc[i][j]);
        }
    }

    m2l[t] = m2acc;
    if (t < 64) n2l[t] = n2acc;
    __syncthreads();

    // selection, one token row at a time
    for (int i = 0; i < 8; ++i) {
        int nloc = r * 8 + i;
        float n2v = n2l[nloc];
        float e0d = FLT_MAX, e1d = FLT_MAX, e2d = FLT_MAX;
        int e0m = 0x7fffffff, e1m = 0x7fffffff, e2m = 0x7fffffff;
#pragma unroll
        for (int j = 0; j < 8; ++j) {
            int m = cl * 8 + j;
            float t1 = __fadd_rn(n2v, m2l[m]);         // n2 + m2
            float d = __fadd_rn(t1, -2.0f * acc[i][j]); // - 2*dot (2*acc exact)
            INSERT_E(d, m);
        }
#pragma unroll
        for (int mask = 1; mask <= 16; mask <<= 1) {
            float f0 = __shfl_xor(e0d, mask); int g0 = __shfl_xor(e0m, mask);
            float f1 = __shfl_xor(e1d, mask); int g1 = __shfl_xor(e1m, mask);
            float f2 = __shfl_xor(e2d, mask); int g2 = __shfl_xor(e2m, mask);
            INSERT_E(f0, g0);
            INSERT_E(f1, g1);
            INSERT_E(f2, g2);
        }
        if (cl == 0) {
            int n = h * 64 + nloc;
            int* op = idx + ((size_t)b * NTOK + n) * NK;
            op[0] = e0m; op[1] = e1m; op[2] = e2m;
        }
    }
}

// ---------------------------------------------------------------------------
// Kernel 4: out = bias + Z[...,idx0,:] + Z[...,idx1,:] + Z[...,idx2,:],
// pixel-shuffled. Block = one h-row (64 tokens). Stage via padded LDS so the
// final global write is fully coalesced.
// ---------------------------------------------------------------------------
__global__ __launch_bounds__(256) void k_out(const float* __restrict__ Z,
                                             const int* __restrict__ idx,
                                             const float* __restrict__ bias,
                                             float* __restrict__ out) {
    __shared__ float staged[64 * 65];
    int b = blockIdx.x >> 6, h = blockIdx.x & 63;
    int t = threadIdx.x;
    int o = t & 63, wv = t >> 6;
    float bv = bias[o];
    const float* zb = Z + (size_t)b * 3 * NM * NC;
    const int* ib = idx + (size_t)b * NTOK * NK;
    for (int ti = 0; ti < 16; ++ti) {
        int w = wv * 16 + ti;
        int n = h * 64 + w;
        const int* ip = ib + (size_t)n * NK;       // wave-uniform
        int i0 = ip[0], i1 = ip[1], i2 = ip[2];
        float v = bv + zb[(size_t)i0 * NC + o]
                     + zb[(size_t)(NM + i1) * NC + o]
                     + zb[(size_t)(2 * NM + i2) * NC + o];
        staged[o * 65 + w] = v;                    // (o+w)%32 banks: conflict-free
    }
    __syncthreads();
    float* ob = out + (size_t)b * 16 * 128 * 128;
#pragma unroll
    for (int it = 0; it < 16; ++it) {
        int flat = t + it * 256;                   // 0..4095
        int W = flat & 127, sh = (flat >> 7) & 1, cc = flat >> 8;
        int oo = cc * 4 + sh * 2 + (W & 1);
        ob[((size_t)cc * 128 + 2 * h + sh) * 128 + W] = staged[oo * 65 + (W >> 1)];
    }
}

// ---------------------------------------------------------------------------
extern "C" void kernel_launch(void* const* d_in, const int* in_sizes, int n_in,
                              void* d_out, int out_size, void* d_ws, size_t ws_size,
                              hipStream_t stream) {
    const float* x    = (const float*)d_in[0];
    const float* w    = (const float*)d_in[1];
    const float* bias = (const float*)d_in[2];
    float* out = (float*)d_out;
    float* ws  = (float*)d_ws;

    // workspace layout (floats):
    float* xs_t = ws;                          // 32*64*256   = 524288
    float* xs_m = ws + 524288;                 // 32*256*64   = 524288
    float* Z    = ws + 1048576;                // 32*3*256*64 = 1572864
    int*   idxb = (int*)(ws + 2621440);        // 32*4096*3   = 393216 ints
    // total ~12 MB

    hipLaunchKernelGGL(k_xs,   dim3(NB),          dim3(256), 0, stream, x, xs_t, xs_m);
    hipLaunchKernelGGL(k_z,    dim3(NB * 3 * 16), dim3(64),  0, stream, xs_m, w, Z);
    hipLaunchKernelGGL(k_dist, dim3(NB * 64),     dim3(256), 0, stream, x, xs_t, idxb);
    hipLaunchKernelGGL(k_out,  dim3(NB * 64),     dim3(256), 0, stream, Z, idxb, bias, out);
}